// Round 2
// baseline (507.622 us; speedup 1.0000x reference)
//
#include <hip/hip_runtime.h>

#define BS 16
#define CI 2048
#define NI 16
#define CO 64
#define NO 32
#define KK 2048  // CO*NO

// MODE 0: iter1 (uniform route) -> accumulate raw vote sums
// MODE 1: iter2 (logits = dist, write logits)
// MODE 2: iter3 (logits = stored + dist, no write)
template <int MODE>
__global__ __launch_bounds__(512) void pass_kernel(
    const float* __restrict__ x,      // [BS][CI][NI]
    const float* __restrict__ w,      // [CI][NI][KK]
    const float* __restrict__ act_in, // [BS][KK] (null for MODE 0)
    float* __restrict__ logits,       // [BS][CI][CO]
    float* __restrict__ partials,     // [G][BS][KK]
    int G)
{
    __shared__ float sm[BS * 65];     // [b][co] padded stride 65

    const int t = threadIdx.x;        // 0..511
    const int blk = blockIdx.x;
    const int k0 = 4 * t;             // this thread's quad of k
    const int co = t >> 3;            // k0/32

    float4 acc[BS];
#pragma unroll
    for (int b = 0; b < BS; ++b) acc[b] = make_float4(0.f, 0.f, 0.f, 0.f);

    for (int i = blk; i < CI; i += G) {
        const float* wrow = w + ((size_t)i * NI) * KK + k0;

        // ---- votes: v[b] = sum_ni x[b,i,ni] * w[i,ni,k0..k0+3] ----
        float4 v[BS];
        if constexpr (MODE != 0) {
#pragma unroll
            for (int b = 0; b < BS; ++b) v[b] = make_float4(0.f, 0.f, 0.f, 0.f);
        }

#pragma unroll
        for (int nig = 0; nig < 4; ++nig) {
            float4 wr0 = *(const float4*)(wrow + (size_t)(nig * 4 + 0) * KK);
            float4 wr1 = *(const float4*)(wrow + (size_t)(nig * 4 + 1) * KK);
            float4 wr2 = *(const float4*)(wrow + (size_t)(nig * 4 + 2) * KK);
            float4 wr3 = *(const float4*)(wrow + (size_t)(nig * 4 + 3) * KK);
#pragma unroll
            for (int b = 0; b < BS; ++b) {
                // block-uniform address -> scalar (s_load) x values
                float4 xv = *(const float4*)&x[((size_t)b * CI + i) * NI + nig * 4];
                float4& vv = (MODE == 0) ? acc[b] : v[b];
                vv.x = fmaf(xv.x, wr0.x, vv.x);
                vv.y = fmaf(xv.x, wr0.y, vv.y);
                vv.z = fmaf(xv.x, wr0.z, vv.z);
                vv.w = fmaf(xv.x, wr0.w, vv.w);
                vv.x = fmaf(xv.y, wr1.x, vv.x);
                vv.y = fmaf(xv.y, wr1.y, vv.y);
                vv.z = fmaf(xv.y, wr1.z, vv.z);
                vv.w = fmaf(xv.y, wr1.w, vv.w);
                vv.x = fmaf(xv.z, wr2.x, vv.x);
                vv.y = fmaf(xv.z, wr2.y, vv.y);
                vv.z = fmaf(xv.z, wr2.z, vv.z);
                vv.w = fmaf(xv.z, wr2.w, vv.w);
                vv.x = fmaf(xv.w, wr3.x, vv.x);
                vv.y = fmaf(xv.w, wr3.y, vv.y);
                vv.z = fmaf(xv.w, wr3.z, vv.z);
                vv.w = fmaf(xv.w, wr3.w, vv.w);
            }
        }

        if constexpr (MODE != 0) {
            // ---- distances: dp[b] = sum_no v[b,co,no]*act[b,co,no] ----
            float dp[BS];
#pragma unroll
            for (int b = 0; b < BS; ++b) {
                float4 a = *(const float4*)&act_in[(size_t)b * KK + k0];
                dp[b] = v[b].x * a.x + v[b].y * a.y + v[b].z * a.z + v[b].w * a.w;
            }
            // reduce over the 8-lane group sharing this co
#pragma unroll
            for (int b = 0; b < BS; ++b) {
#pragma unroll
                for (int m = 1; m < 8; m <<= 1)
                    dp[b] += __shfl_xor(dp[b], m, 8);
            }
            // each of the 8 lanes in the group writes two b's
            {
                int j = t & 7;
                sm[j * 65 + co] = dp[j];
                sm[(j + 8) * 65 + co] = dp[j + 8];
            }
            __syncthreads();

            // ---- softmax over co: thread t handles (b0, cs) and (b0+8, cs) ----
            {
                int b0 = t >> 6;      // 0..7
                int cs = t & 63;
                float d0 = sm[b0 * 65 + cs];
                float d1 = sm[(b0 + 8) * 65 + cs];
                size_t l0 = ((size_t)b0 * CI + i) * CO + cs;
                size_t l1 = ((size_t)(b0 + 8) * CI + i) * CO + cs;
                float lg0, lg1;
                if constexpr (MODE == 1) {
                    lg0 = d0; lg1 = d1;
                    logits[l0] = lg0; logits[l1] = lg1;
                } else {
                    lg0 = logits[l0] + d0;
                    lg1 = logits[l1] + d1;
                }
                float mx0 = lg0, mx1 = lg1;
#pragma unroll
                for (int m = 1; m < 64; m <<= 1) {
                    mx0 = fmaxf(mx0, __shfl_xor(mx0, m, 64));
                    mx1 = fmaxf(mx1, __shfl_xor(mx1, m, 64));
                }
                float e0 = __expf(lg0 - mx0), e1 = __expf(lg1 - mx1);
                float s0 = e0, s1 = e1;
#pragma unroll
                for (int m = 1; m < 64; m <<= 1) {
                    s0 += __shfl_xor(s0, m, 64);
                    s1 += __shfl_xor(s1, m, 64);
                }
                sm[b0 * 65 + cs] = e0 / s0;
                sm[(b0 + 8) * 65 + cs] = e1 / s1;
            }
            __syncthreads();

            // ---- routed accumulate ----
#pragma unroll
            for (int b = 0; b < BS; ++b) {
                float r = sm[b * 65 + co];
                acc[b].x = fmaf(r, v[b].x, acc[b].x);
                acc[b].y = fmaf(r, v[b].y, acc[b].y);
                acc[b].z = fmaf(r, v[b].z, acc[b].z);
                acc[b].w = fmaf(r, v[b].w, acc[b].w);
            }
            __syncthreads();  // protect sm before next i overwrites it
        }
    }

    // write per-block partial preactivations
#pragma unroll
    for (int b = 0; b < BS; ++b) {
        *(float4*)&partials[((size_t)blk * BS + b) * KK + k0] = acc[b];
    }
}

__global__ __launch_bounds__(256) void reduce_squash(
    const float* __restrict__ partials, int G,
    const float* __restrict__ bias,
    float* __restrict__ act_out, float scale)
{
    int tid = blockIdx.x * 256 + threadIdx.x;  // 0..32767
    int b = tid >> 11;    // /KK
    int k = tid & (KK - 1);
    const float* p = partials + (size_t)b * KK + k;
    const size_t stride = (size_t)BS * KK;
    float s0 = 0.f, s1 = 0.f, s2 = 0.f, s3 = 0.f;
    for (int g = 0; g < G; g += 4) {
        s0 += p[(size_t)g * stride];
        s1 += p[(size_t)(g + 1) * stride];
        s2 += p[(size_t)(g + 2) * stride];
        s3 += p[(size_t)(g + 3) * stride];
    }
    float v = (s0 + s1) + (s2 + s3);
    v = v * scale + bias[k];
    // squash over the 32-no group (consecutive lanes, 32-aligned)
    float n2 = v * v;
#pragma unroll
    for (int m = 1; m < 32; m <<= 1) n2 += __shfl_xor(n2, m, 32);
    float norm = sqrtf(n2);
    act_out[tid] = v * norm / (1.f + n2);
}

extern "C" void kernel_launch(void* const* d_in, const int* in_sizes, int n_in,
                              void* d_out, int out_size, void* d_ws, size_t ws_size,
                              hipStream_t stream) {
    const float* x = (const float*)d_in[0];
    const float* w = (const float*)d_in[1];
    const float* bias = (const float*)d_in[2];
    float* out = (float*)d_out;

    // workspace layout: partials[G][BS][KK] | logits[BS][CI][CO] | act1 | act2
    const size_t fixed = (size_t)BS * CI * CO * 4 + 2 * (size_t)BS * KK * 4;
    int G = 256;
    while (G > 8 && fixed + (size_t)G * BS * KK * 4 > ws_size) G >>= 1;

    char* p = (char*)d_ws;
    float* partials = (float*)p; p += (size_t)G * BS * KK * 4;
    float* logits = (float*)p;   p += (size_t)BS * CI * CO * 4;
    float* act1 = (float*)p;     p += (size_t)BS * KK * 4;
    float* act2 = (float*)p;

    dim3 blk(512), grid(G);
    // iteration 1 (uniform route)
    pass_kernel<0><<<grid, blk, 0, stream>>>(x, w, nullptr, logits, partials, G);
    reduce_squash<<<128, 256, 0, stream>>>(partials, G, bias, act1, 1.0f / (float)CO);
    // iteration 2
    pass_kernel<1><<<grid, blk, 0, stream>>>(x, w, act1, logits, partials, G);
    reduce_squash<<<128, 256, 0, stream>>>(partials, G, bias, act2, 1.0f);
    // iteration 3 (final; logit update after is dead in the reference)
    pass_kernel<2><<<grid, blk, 0, stream>>>(x, w, act2, logits, partials, G);
    reduce_squash<<<128, 256, 0, stream>>>(partials, G, bias, out, 1.0f);
}